// Round 1
// baseline (454.460 us; speedup 1.0000x reference)
//
#include <hip/hip_runtime.h>
#include <hip/hip_bf16.h>

// 3-layer MLP matvec chain, fp32, memory-bound on weight reads (~417 MB total).
// Structure: one block (256 threads) per output row; float4 coalesced weight
// loads (16 B/lane); wave shuffle reduce + tiny LDS cross-wave reduce; bias +
// optional square fused into the epilogue. Three sequential kernel launches
// give the required h1 -> h2 -> out ordering (kernel boundaries handle
// cross-XCD coherence).

__global__ __launch_bounds__(256) void matvec_rowblock(
    const float* __restrict__ W,   // rows x K, row-major
    const float* __restrict__ x,   // K
    const float* __restrict__ bias,// rows
    float* __restrict__ y,         // rows
    int K, int do_square)
{
    const int row = blockIdx.x;
    const int tid = threadIdx.x;
    const float4* __restrict__ W4 = (const float4*)(W + (size_t)row * (size_t)K);
    const float4* __restrict__ x4 = (const float4*)x;
    const int K4 = K >> 2;

    float acc = 0.0f;
    // 256 threads, float4 each: 4096 B per block-iteration. K=4096 -> 4 iters,
    // K=8192 -> 8 iters per thread. Fully coalesced, 16 B/lane.
    for (int i = tid; i < K4; i += 256) {
        float4 w = W4[i];
        float4 v = x4[i];
        acc += w.x * v.x + w.y * v.y + w.z * v.z + w.w * v.w;
    }

    // wave=64 reduce
    #pragma unroll
    for (int off = 32; off > 0; off >>= 1)
        acc += __shfl_down(acc, off, 64);

    __shared__ float wsum[4];
    const int wave = tid >> 6;
    const int lane = tid & 63;
    if (lane == 0) wsum[wave] = acc;
    __syncthreads();

    if (tid == 0) {
        float s = (wsum[0] + wsum[1]) + (wsum[2] + wsum[3]);
        s += bias[row];
        if (do_square) s = s * s;
        y[row] = s;
    }
}

extern "C" void kernel_launch(void* const* d_in, const int* in_sizes, int n_in,
                              void* d_out, int out_size, void* d_ws, size_t ws_size,
                              hipStream_t stream) {
    const float* x  = (const float*)d_in[0];
    const float* W1 = (const float*)d_in[1];
    const float* b1 = (const float*)d_in[2];
    const float* W2 = (const float*)d_in[3];
    const float* b2 = (const float*)d_in[4];
    const float* W3 = (const float*)d_in[5];
    const float* b3 = (const float*)d_in[6];
    float* out = (float*)d_out;

    const int D_IN = 4096, D_HID = 8192, D_OUT = 1000;

    float* h1 = (float*)d_ws;          // 8192 floats
    float* h2 = h1 + D_HID;            // 8192 floats

    // layer 1: h1 = (W1 @ x + b1)^2   -- 128 MiB of W1
    matvec_rowblock<<<D_HID, 256, 0, stream>>>(W1, x, b1, h1, D_IN, 1);
    // layer 2: h2 = (W2 @ h1 + b2)^2  -- 256 MiB of W2
    matvec_rowblock<<<D_HID, 256, 0, stream>>>(W2, h1, b2, h2, D_HID, 1);
    // layer 3: out = W3 @ h2 + b3     -- 32.8 MB of W3
    matvec_rowblock<<<D_OUT, 256, 0, stream>>>(W3, h2, b3, out, D_HID, 0);
}

// Round 2
// 448.165 us; speedup vs baseline: 1.0140x; 1.0140x over previous
//
#include <hip/hip_runtime.h>
#include <hip/hip_bf16.h>

// 3-layer MLP matvec chain, fp32, HBM-bound on weight reads (~417 MB total).
// R1 lesson: runtime-trip-count loop + serial accumulator => ~2 loads in
// flight per wave => latency-bound at ~0.9 TB/s. Fix: compile-time K so the
// per-thread loop (4 or 8 iters) fully unrolls, and 2 rows per block with a
// shared x load (two independent acc chains, ~3x load streams, half the
// redundant x traffic).

template<int K>
__global__ __launch_bounds__(256) void matvec2row(
    const float* __restrict__ W,    // nrows x K row-major
    const float* __restrict__ x,    // K
    const float* __restrict__ bias, // nrows
    float* __restrict__ y,          // nrows
    int do_square)
{
    constexpr int K4   = K / 4;     // float4 elements per row
    constexpr int ITER = K4 / 256;  // 4 (K=4096) or 8 (K=8192)
    const int row0 = blockIdx.x * 2;
    const int tid  = threadIdx.x;

    const float4* __restrict__ Wa = (const float4*)(W + (size_t)row0 * K);
    const float4* __restrict__ Wb = (const float4*)(W + (size_t)(row0 + 1) * K);
    const float4* __restrict__ x4 = (const float4*)x;

    float acc0 = 0.0f, acc1 = 0.0f;
    #pragma unroll
    for (int it = 0; it < ITER; ++it) {
        const int i = tid + it * 256;   // coalesced: 256 lanes x 16 B contiguous
        float4 v  = x4[i];
        float4 wa = Wa[i];
        float4 wb = Wb[i];
        acc0 += wa.x * v.x + wa.y * v.y + wa.z * v.z + wa.w * v.w;
        acc1 += wb.x * v.x + wb.y * v.y + wb.z * v.z + wb.w * v.w;
    }

    // wave-64 butterfly reduce on both accumulators
    #pragma unroll
    for (int off = 32; off > 0; off >>= 1) {
        acc0 += __shfl_down(acc0, off, 64);
        acc1 += __shfl_down(acc1, off, 64);
    }

    __shared__ float s0[4], s1[4];
    const int wave = tid >> 6;
    if ((tid & 63) == 0) { s0[wave] = acc0; s1[wave] = acc1; }
    __syncthreads();

    if (tid == 0) {
        float r0 = (s0[0] + s0[1]) + (s0[2] + s0[3]);
        float r1 = (s1[0] + s1[1]) + (s1[2] + s1[3]);
        r0 += bias[row0];
        r1 += bias[row0 + 1];
        if (do_square) { r0 = r0 * r0; r1 = r1 * r1; }
        y[row0]     = r0;
        y[row0 + 1] = r1;
    }
}

extern "C" void kernel_launch(void* const* d_in, const int* in_sizes, int n_in,
                              void* d_out, int out_size, void* d_ws, size_t ws_size,
                              hipStream_t stream) {
    const float* x  = (const float*)d_in[0];
    const float* W1 = (const float*)d_in[1];
    const float* b1 = (const float*)d_in[2];
    const float* W2 = (const float*)d_in[3];
    const float* b2 = (const float*)d_in[4];
    const float* W3 = (const float*)d_in[5];
    const float* b3 = (const float*)d_in[6];
    float* out = (float*)d_out;

    const int D_HID = 8192, D_OUT = 1000;

    float* h1 = (float*)d_ws;          // 8192 floats
    float* h2 = h1 + D_HID;            // 8192 floats

    // layer 1: h1 = (W1 @ x + b1)^2   -- 128 MiB of W1, K=4096
    matvec2row<4096><<<D_HID / 2, 256, 0, stream>>>(W1, x, b1, h1, 1);
    // layer 2: h2 = (W2 @ h1 + b2)^2  -- 256 MiB of W2, K=8192
    matvec2row<8192><<<D_HID / 2, 256, 0, stream>>>(W2, h1, b2, h2, 1);
    // layer 3: out = W3 @ h2 + b3     -- 32.8 MB of W3, K=8192, 1000 rows
    matvec2row<8192><<<D_OUT / 2, 256, 0, stream>>>(W3, h2, b3, out, 0);
}